// Round 2
// baseline (38.501 us; speedup 1.0000x reference)
//
#include <hip/hip_runtime.h>
#include <hip/hip_cooperative_groups.h>

namespace cg = cooperative_groups;

// WeightedCenterLoss:
//   c = centers[labels]; d = ||x||^2 + ||c||^2 - 2 x.c
//   v = clip(d * class_weights[labels], 1e-12, 1e12)
//   loss = (sum(v) + B*(C-1)*1e-12) / B
//
// B=2048, D=256, C=50000. ~4.2 MB reads -> latency/launch bound (data floor
// ~0.7us). Round 1 (two kernel nodes) = 13.3us -> node overhead dominates.
// This round: ONE cooperative kernel, grid.sync() between per-block partials
// and the final 256-element reduction. Fixed-order sums -> deterministic.

constexpr int B = 2048;
constexpr int D = 256;
constexpr int C = 50000;
constexpr int BLOCKS = 256;   // 1 block per CU
constexpr int TPB = 512;      // 8 waves per block, 1 sample per wave

__global__ __launch_bounds__(TPB) void wcl_fused(
    const float* __restrict__ x, const float* __restrict__ centers,
    const float* __restrict__ cw, const int* __restrict__ labels,
    float* __restrict__ partial, float* __restrict__ out) {
  __shared__ float sm[8];
  const int lane = threadIdx.x & 63;
  const int w = (int)(threadIdx.x >> 6);          // wave id in block, 0..7
  const int s = (int)blockIdx.x * 8 + w;          // sample id, 0..2047

  // Independent loads issue together; label->centers is the one dependent hop.
  const int lbl = labels[s];
  const float4 xv = reinterpret_cast<const float4*>(x + (size_t)s * D)[lane];
  const float4 cv = reinterpret_cast<const float4*>(centers + (size_t)lbl * D)[lane];

  const float xx = xv.x * xv.x + xv.y * xv.y + xv.z * xv.z + xv.w * xv.w;
  const float cc = cv.x * cv.x + cv.y * cv.y + cv.z * cv.z + cv.w * cv.w;
  const float xc = xv.x * cv.x + xv.y * cv.y + xv.z * cv.z + xv.w * cv.w;
  float acc = xx + cc - 2.0f * xc;

#pragma unroll
  for (int off = 32; off > 0; off >>= 1) acc += __shfl_xor(acc, off, 64);

  if (lane == 0) {
    float v = acc * cw[lbl];
    sm[w] = fminf(fmaxf(v, 1e-12f), 1e12f);
  }
  __syncthreads();
  if (threadIdx.x == 0) {
    float t = 0.0f;
#pragma unroll
    for (int i = 0; i < 8; ++i) t += sm[i];
    partial[blockIdx.x] = t;  // fixed order -> deterministic
  }

  cg::this_grid().sync();

  if (blockIdx.x == 0) {
    float p = (threadIdx.x < BLOCKS) ? partial[threadIdx.x] : 0.0f;
#pragma unroll
    for (int off = 32; off > 0; off >>= 1) p += __shfl_xor(p, off, 64);
    if (lane == 0) sm[w] = p;   // reuse sm; phase-1 value already consumed
    __syncthreads();
    if (threadIdx.x == 0) {
      float tot = 0.0f;
#pragma unroll
      for (int i = 0; i < 8; ++i) tot += sm[i];
      // off-mask constant: float32(B*(C-1)) * float32(1e-12), exact in f32
      const float off_const = 102397952.0f * 1e-12f;
      out[0] = (tot + off_const) / 2048.0f;
    }
  }
}

extern "C" void kernel_launch(void* const* d_in, const int* in_sizes, int n_in,
                              void* d_out, int out_size, void* d_ws, size_t ws_size,
                              hipStream_t stream) {
  const float* x       = (const float*)d_in[0];
  const float* centers = (const float*)d_in[1];
  const float* cw      = (const float*)d_in[2];
  const int*   labels  = (const int*)d_in[3];
  float* out = (float*)d_out;
  float* partial = (float*)d_ws;  // 256 floats; overwritten before read each call

  void* args[] = {(void*)&x, (void*)&centers, (void*)&cw, (void*)&labels,
                  (void*)&partial, (void*)&out};
  hipLaunchCooperativeKernel((const void*)wcl_fused, dim3(BLOCKS), dim3(TPB),
                             args, 0, stream);
}

// Round 3
// 11.311 us; speedup vs baseline: 3.4040x; 3.4040x over previous
//
#include <hip/hip_runtime.h>

// WeightedCenterLoss:
//   c = centers[labels]; d = ||x||^2 + ||c||^2 - 2 x.c
//   v = clip(d * class_weights[labels], 1e-12, 1e12)
//   loss = (sum(v) + B*(C-1)*1e-12) / B
//
// B=2048, D=256, C=50000. ~4.2 MB reads; data floor ~0.7us -> launch/latency
// bound. R1 two-node = 13.3us. R2 cooperative single-node = 38.5us (coop
// launch doesn't graph-replay cheaply) -> REVERTED.
// R3: two-node, minimized: k1 = 256 blocks x 512 thr, block partials (256
// floats); k2 = ONE 64-lane wave, float4 loads, shuffle-only reduce.

constexpr int B = 2048;
constexpr int D = 256;
constexpr int C = 50000;
constexpr int BLOCKS = 256;
constexpr int TPB = 512;   // 8 waves = 8 samples per block

__global__ __launch_bounds__(TPB) void wcl_partials(
    const float* __restrict__ x, const float* __restrict__ centers,
    const float* __restrict__ cw, const int* __restrict__ labels,
    float* __restrict__ partial) {
  __shared__ float sm[8];
  const int lane = threadIdx.x & 63;
  const int w = (int)(threadIdx.x >> 6);
  const int s = (int)blockIdx.x * 8 + w;

  const int lbl = labels[s];  // dependent hop #1
  const float4 xv = reinterpret_cast<const float4*>(x + (size_t)s * D)[lane];
  const float4 cv = reinterpret_cast<const float4*>(centers + (size_t)lbl * D)[lane];

  const float xx = xv.x * xv.x + xv.y * xv.y + xv.z * xv.z + xv.w * xv.w;
  const float cc = cv.x * cv.x + cv.y * cv.y + cv.z * cv.z + cv.w * cv.w;
  const float xc = xv.x * cv.x + xv.y * cv.y + xv.z * cv.z + xv.w * cv.w;
  float acc = xx + cc - 2.0f * xc;

#pragma unroll
  for (int off = 32; off > 0; off >>= 1) acc += __shfl_xor(acc, off, 64);

  if (lane == 0) {
    float v = acc * cw[lbl];
    sm[w] = fminf(fmaxf(v, 1e-12f), 1e12f);
  }
  __syncthreads();
  if (threadIdx.x == 0) {
    float t = 0.0f;
#pragma unroll
    for (int i = 0; i < 8; ++i) t += sm[i];
    partial[blockIdx.x] = t;  // fixed order -> deterministic
  }
}

__global__ __launch_bounds__(64) void wcl_final(
    const float* __restrict__ partial, float* __restrict__ out) {
  const int lane = threadIdx.x;  // 64 lanes, one wave
  const float4 p = reinterpret_cast<const float4*>(partial)[lane];
  float s = (p.x + p.y) + (p.z + p.w);
#pragma unroll
  for (int off = 32; off > 0; off >>= 1) s += __shfl_xor(s, off, 64);
  if (lane == 0) {
    const float off_const = 102397952.0f * 1e-12f;  // f32(B*(C-1)) * 1e-12
    out[0] = (s + off_const) / 2048.0f;
  }
}

extern "C" void kernel_launch(void* const* d_in, const int* in_sizes, int n_in,
                              void* d_out, int out_size, void* d_ws, size_t ws_size,
                              hipStream_t stream) {
  const float* x       = (const float*)d_in[0];
  const float* centers = (const float*)d_in[1];
  const float* cw      = (const float*)d_in[2];
  const int*   labels  = (const int*)d_in[3];
  float* out = (float*)d_out;
  float* partial = (float*)d_ws;  // 256 floats; fully rewritten every call

  wcl_partials<<<BLOCKS, TPB, 0, stream>>>(x, centers, cw, labels, partial);
  wcl_final<<<1, 64, 0, stream>>>(partial, out);
}

// Round 4
// 11.185 us; speedup vs baseline: 3.4422x; 1.0112x over previous
//
#include <hip/hip_runtime.h>

// WeightedCenterLoss:
//   c = centers[labels]; d = ||x||^2 + ||c||^2 - 2 x.c
//   v = clip(d * class_weights[labels], 1e-12, 1e12)
//   loss = (sum(v) + B*(C-1)*1e-12) / B
//
// B=2048, D=256, C=50000. ~4.2 MB reads; data floor ~0.7us -> the 11.3us R3
// time is ~90% two-node dispatch overhead. Single-node is unsound (init-free
// last-block detection impossible under poison-once/no-state contract);
// cooperative launch = 38.5us (R2). So: shave execution inside the 2 nodes.
// R4: k1 has NO LDS / NO barrier -- each wave writes its own sample's value
// straight to partial[s]; k2 = one wave, 8x float4/lane over 2048 L2-hot
// floats. Fixed-order sums -> deterministic, absmax 0 expected.

constexpr int B = 2048;
constexpr int D = 256;
constexpr int C = 50000;
constexpr int BLOCKS = 256;
constexpr int TPB = 512;   // 8 waves = 8 samples per block

__global__ __launch_bounds__(TPB) void wcl_persample(
    const float* __restrict__ x, const float* __restrict__ centers,
    const float* __restrict__ cw, const int* __restrict__ labels,
    float* __restrict__ partial) {
  const int lane = threadIdx.x & 63;
  const int s = (int)blockIdx.x * 8 + (int)(threadIdx.x >> 6);

  const int lbl = labels[s];  // dependent hop: label -> center row
  const float4 xv = reinterpret_cast<const float4*>(x + (size_t)s * D)[lane];
  const float4 cv = reinterpret_cast<const float4*>(centers + (size_t)lbl * D)[lane];

  const float xx = xv.x * xv.x + xv.y * xv.y + xv.z * xv.z + xv.w * xv.w;
  const float cc = cv.x * cv.x + cv.y * cv.y + cv.z * cv.z + cv.w * cv.w;
  const float xc = xv.x * cv.x + xv.y * cv.y + xv.z * cv.z + xv.w * cv.w;
  float acc = xx + cc - 2.0f * xc;

#pragma unroll
  for (int off = 32; off > 0; off >>= 1) acc += __shfl_xor(acc, off, 64);

  if (lane == 0) {
    float v = acc * cw[lbl];
    partial[s] = fminf(fmaxf(v, 1e-12f), 1e12f);  // no LDS, no barrier, done
  }
}

__global__ __launch_bounds__(64) void wcl_final(
    const float* __restrict__ partial, float* __restrict__ out) {
  const int lane = threadIdx.x;  // one wave
  const float4* p4 = reinterpret_cast<const float4*>(partial);
  float s = 0.0f;
#pragma unroll
  for (int i = 0; i < 8; ++i) {  // 8 independent L2-hot loads in flight
    const float4 p = p4[lane + 64 * i];
    s += (p.x + p.y) + (p.z + p.w);
  }
#pragma unroll
  for (int off = 32; off > 0; off >>= 1) s += __shfl_xor(s, off, 64);
  if (lane == 0) {
    const float off_const = 102397952.0f * 1e-12f;  // f32(B*(C-1)) * 1e-12
    out[0] = (s + off_const) / 2048.0f;
  }
}

extern "C" void kernel_launch(void* const* d_in, const int* in_sizes, int n_in,
                              void* d_out, int out_size, void* d_ws, size_t ws_size,
                              hipStream_t stream) {
  const float* x       = (const float*)d_in[0];
  const float* centers = (const float*)d_in[1];
  const float* cw      = (const float*)d_in[2];
  const int*   labels  = (const int*)d_in[3];
  float* out = (float*)d_out;
  float* partial = (float*)d_ws;  // 2048 floats; fully rewritten every call

  wcl_persample<<<BLOCKS, TPB, 0, stream>>>(x, centers, cw, labels, partial);
  wcl_final<<<1, 64, 0, stream>>>(partial, out);
}